// Round 10
// baseline (12.311 us; speedup 1.0000x reference)
//
#include <hip/hip_runtime.h>

#define N_QUERIES 2097152

typedef float fx4 __attribute__((ext_vector_type(4)));

// Per query: 2x b128 position-pair gathers + 1x b128 color gather.
__device__ __forceinline__ fx4 nearest_col(float qx, float qy,
                                           const fx4* pr, const fx4* cl)
{
    // nearest 2x2 cell-center block; jitter margin (0.1179 vs 0.0955) proves
    // the global argmin over all 64 jittered sites lies in this block.
    float fx = qx * 8.0f - 0.5f;
    float fy = qy * 8.0f - 0.5f;
    float fi = fminf(fmaxf(floorf(fx), 0.0f), 6.0f);
    float fj = fminf(fmaxf(floorf(fy), 0.0f), 6.0f);
    int k0 = (int)fi * 8 + (int)fj;

    fx4 r0 = pr[k0];       // {px[k0],py[k0],px[k0+1],py[k0+1]}
    fx4 r1 = pr[k0 + 8];   // {px[k0+8],py[k0+8],px[k0+9],py[k0+9]}

    // ascending k + strict '<' == np.argmin tie-break;
    // __fmul_rn/__fadd_rn match numpy's separate roundings (no FMA).
    float dx, dy, d2, best;
    int bk = k0;
    dx = qx - r0.x; dy = qy - r0.y;
    best = __fadd_rn(__fmul_rn(dx, dx), __fmul_rn(dy, dy));
    dx = qx - r0.z; dy = qy - r0.w;
    d2 = __fadd_rn(__fmul_rn(dx, dx), __fmul_rn(dy, dy));
    if (d2 < best) { best = d2; bk = k0 + 1; }
    dx = qx - r1.x; dy = qy - r1.y;
    d2 = __fadd_rn(__fmul_rn(dx, dx), __fmul_rn(dy, dy));
    if (d2 < best) { best = d2; bk = k0 + 8; }
    dx = qx - r1.z; dy = qy - r1.w;
    d2 = __fadd_rn(__fmul_rn(dx, dx), __fmul_rn(dy, dy));
    if (d2 < best) { best = d2; bk = k0 + 9; }

    return cl[bk];
}

// Two software-pipelined tiles of 512 queries per block: both tile loads are
// in flight before tile-0 compute; tile-0 stores overlap tile-1 compute.
// Breaks the one-generation read-burst / compute / write-burst serialization.
__global__ __launch_bounds__(256) void voronoi_kernel(
    const float* __restrict__ x,
    const float* __restrict__ p,
    float* __restrict__ out)
{
    __shared__ fx4 pairs[64];      // shared site tables (read-only after build)
    __shared__ fx4 cols [64];
    __shared__ fx4 oc[4][2][96];   // per-wave double-buffered staging (128 q x 3)

    const int tid  = threadIdx.x;
    const int wid  = tid >> 6;
    const int lane = tid & 63;

    const fx4* __restrict__ x4 = (const fx4*)x + (size_t)blockIdx.x * 512;

    // tile-0 load first (in flight during table build + barrier)
    fx4 v0 = x4[64 * wid + lane];            // queries: tile0, wave-rel 2L,2L+1

    if (tid < 64) {
        const float* ps = p + tid * 5;
        int nb = ((tid & 7) == 7) ? tid : tid + 1;   // col+1 neighbor (col=7 never read)
        const float* pn = p + nb * 5;
        pairs[tid] = fx4{ps[0], ps[1], pn[0], pn[1]};
        cols [tid] = fx4{ps[2], ps[3], ps[4], 0.0f};
    }
    __syncthreads();   // tables ready; waves decouple after this

    // tile-1 load issued BEFORE tile-0 compute (read stream extends through kernel)
    fx4 v1 = x4[256 + 64 * wid + lane];

    fx4* __restrict__ obase = (fx4*)out + (size_t)blockIdx.x * 768 + 96 * wid;

    // ---------------- tile 0 ----------------
    {
        fx4 c0 = nearest_col(v0.x, v0.y, pairs, cols);
        fx4 c1 = nearest_col(v0.z, v0.w, pairs, cols);
        float* o = (float*)&oc[wid][0][0] + 6 * lane;
        o[0] = c0.x; o[1] = c0.y; o[2] = c0.z;
        o[3] = c1.x; o[4] = c1.y; o[5] = c1.z;
        // within-wave LDS RAW: HW DS pipe in-order per wave; fence the compiler
        asm volatile("s_waitcnt lgkmcnt(0)" ::: "memory");
        __builtin_amdgcn_sched_barrier(0);
        const fx4* ocv = &oc[wid][0][0];
        __builtin_nontemporal_store(ocv[lane], &obase[lane]);
        if (lane < 32)
            __builtin_nontemporal_store(ocv[64 + lane], &obase[64 + lane]);
    }

    // ---------------- tile 1 ----------------
    {
        fx4 c0 = nearest_col(v1.x, v1.y, pairs, cols);
        fx4 c1 = nearest_col(v1.z, v1.w, pairs, cols);
        float* o = (float*)&oc[wid][1][0] + 6 * lane;
        o[0] = c0.x; o[1] = c0.y; o[2] = c0.z;
        o[3] = c1.x; o[4] = c1.y; o[5] = c1.z;
        asm volatile("s_waitcnt lgkmcnt(0)" ::: "memory");
        __builtin_amdgcn_sched_barrier(0);
        const fx4* ocv = &oc[wid][1][0];
        fx4* __restrict__ ob = obase + 384;   // tile1 = +512 queries = +384 fx4
        __builtin_nontemporal_store(ocv[lane], &ob[lane]);
        if (lane < 32)
            __builtin_nontemporal_store(ocv[64 + lane], &ob[64 + lane]);
    }
}

extern "C" void kernel_launch(void* const* d_in, const int* in_sizes, int n_in,
                              void* d_out, int out_size, void* d_ws, size_t ws_size,
                              hipStream_t stream) {
    const float* x = (const float*)d_in[0];
    const float* p = (const float*)d_in[1];
    float* out = (float*)d_out;

    const int block = 256;
    const int grid = N_QUERIES / 1024;   // 2048 blocks -> 8/CU, 32 waves/CU
    voronoi_kernel<<<grid, block, 0, stream>>>(x, p, out);
}

// Round 11
// 10.078 us; speedup vs baseline: 1.2216x; 1.2216x over previous
//
#include <hip/hip_runtime.h>

#define N_QUERIES 2097152

typedef float fx4 __attribute__((ext_vector_type(4)));

// Per query: 2x b128 position-pair gathers + 1x b128 color gather.
__device__ __forceinline__ fx4 nearest_col(float qx, float qy,
                                           const fx4* pr, const fx4* cl)
{
    // nearest 2x2 cell-center block; jitter margin (0.1179 vs 0.0955) proves
    // the global argmin over all 64 jittered sites lies in this block.
    float fx = qx * 8.0f - 0.5f;
    float fy = qy * 8.0f - 0.5f;
    float fi = fminf(fmaxf(floorf(fx), 0.0f), 6.0f);
    float fj = fminf(fmaxf(floorf(fy), 0.0f), 6.0f);
    int k0 = (int)fi * 8 + (int)fj;

    fx4 r0 = pr[k0];       // {px[k0],py[k0],px[k0+1],py[k0+1]}
    fx4 r1 = pr[k0 + 8];   // {px[k0+8],py[k0+8],px[k0+9],py[k0+9]}

    // ascending k + strict '<' == np.argmin tie-break;
    // __fmul_rn/__fadd_rn match numpy's separate roundings (no FMA).
    float dx, dy, d2, best;
    int bk = k0;
    dx = qx - r0.x; dy = qy - r0.y;
    best = __fadd_rn(__fmul_rn(dx, dx), __fmul_rn(dy, dy));
    dx = qx - r0.z; dy = qy - r0.w;
    d2 = __fadd_rn(__fmul_rn(dx, dx), __fmul_rn(dy, dy));
    if (d2 < best) { best = d2; bk = k0 + 1; }
    dx = qx - r1.x; dy = qy - r1.y;
    d2 = __fadd_rn(__fmul_rn(dx, dx), __fmul_rn(dy, dy));
    if (d2 < best) { best = d2; bk = k0 + 8; }
    dx = qx - r1.z; dy = qy - r1.w;
    d2 = __fadd_rn(__fmul_rn(dx, dx), __fmul_rn(dy, dy));
    if (d2 < best) { best = d2; bk = k0 + 9; }

    return cl[bk];
}

// 128-thread (2-wave) blocks, 256 queries each, 8192 blocks. Small blocks
// retire at 2-wave granularity, so fresh blocks (load phase) launch while
// older blocks drain stores -> read/write streams interleave in steady state
// instead of the one-generation burst serialization of 1024-query blocks.
__global__ __launch_bounds__(128) void voronoi_kernel(
    const float* __restrict__ x,
    const float* __restrict__ p,
    float* __restrict__ out)
{
    __shared__ fx4 pairs[64];    // shared site tables (read-only after build)
    __shared__ fx4 cols [64];
    __shared__ fx4 oc[2][96];    // per-wave output staging (128 q x 3 floats)

    const int tid  = threadIdx.x;
    const int wid  = tid >> 6;
    const int lane = tid & 63;

    // unit-stride load: lane L of wave w -> queries 2L,2L+1 of wave's 128
    const fx4* __restrict__ x4 =
        (const fx4*)x + (size_t)blockIdx.x * 128 + 64 * wid;
    fx4 a = x4[lane];

    if (tid < 64) {
        const float* ps = p + tid * 5;
        int nb = ((tid & 7) == 7) ? tid : tid + 1;   // col+1 neighbor (col=7 never read)
        const float* pn = p + nb * 5;
        pairs[tid] = fx4{ps[0], ps[1], pn[0], pn[1]};
        cols [tid] = fx4{ps[2], ps[3], ps[4], 0.0f};
    }
    __syncthreads();   // tables ready; waves decouple after this

    fx4 c0 = nearest_col(a.x, a.y, pairs, cols);
    fx4 c1 = nearest_col(a.z, a.w, pairs, cols);

    // stage: lane L -> wave-rel floats [6L, 6L+6)
    float* o = (float*)&oc[wid][0] + 6 * lane;
    o[0] = c0.x; o[1] = c0.y; o[2] = c0.z;
    o[3] = c1.x; o[4] = c1.y; o[5] = c1.z;

    // within-wave LDS RAW: HW DS pipe is in-order per wave; fence the compiler
    asm volatile("s_waitcnt lgkmcnt(0)" ::: "memory");
    __builtin_amdgcn_sched_barrier(0);

    // readback unit-stride, nontemporal store: 96 fx4 per wave
    const fx4* ocv = oc[wid];
    fx4* __restrict__ o4 = (fx4*)out + (size_t)blockIdx.x * 192 + 96 * wid;
    __builtin_nontemporal_store(ocv[lane], &o4[lane]);
    if (lane < 32)
        __builtin_nontemporal_store(ocv[64 + lane], &o4[64 + lane]);
}

extern "C" void kernel_launch(void* const* d_in, const int* in_sizes, int n_in,
                              void* d_out, int out_size, void* d_ws, size_t ws_size,
                              hipStream_t stream) {
    const float* x = (const float*)d_in[0];
    const float* p = (const float*)d_in[1];
    float* out = (float*)d_out;

    const int block = 128;
    const int grid = N_QUERIES / 256;   // 8192 blocks -> ~2 generations of
                                        // 2-wave blocks, per-block recycling
    voronoi_kernel<<<grid, block, 0, stream>>>(x, p, out);
}